// Round 9
// baseline (429.726 us; speedup 1.0000x reference)
//
#include <hip/hip_runtime.h>
#include <math.h>

#define MAX_ITERS 100
#define EPS 1e-12f
// TOL 2e-4 (R7, neutral but safe): certifies ~7e-4 relative distance to the
// fixed point, ~5x under the 3.9e-3 bf16 floor, ~30x under the threshold.
#define TOL 2e-4f

// f32x2 packing (R8): NEUTRAL -- gfx950 FP32 vector peak 157.3TF is the
// non-packed rate; v_pk_fma_f32 has no double-rate path here (unlike gfx90a).
// Kept because it's the measured-green shape; do not expect gains from it.
typedef float f32x2 __attribute__((ext_vector_type(2)));

__device__ __forceinline__ f32x2 splat2(float x) { f32x2 r; r.x = x; r.y = x; return r; }

// v_rcp_f32: <=1 ulp. Proven neutral on absmax (bf16 floor 0.00390625).
__device__ __forceinline__ float fast_rcp(float x) {
    return __builtin_amdgcn_rcpf(x);
}

// _squash = 0.02 + 0.96*sigmoid(x); native exp + rcp.
__device__ __forceinline__ float squash(float x) {
    return 0.02f + 0.96f * fast_rcp(1.0f + __expf(-x));
}

// R9: PERSISTENT WAVES + ATOMIC TICKETS (tail-rebalance hypothesis test).
// R7 (TOL 6.7x looser = neutral) + R8 (issue-halving = neutral) imply the
// N_iter distribution is skewed: average wave ~35 iters but slow items
// (rate ~0.95+) run toward the 100 cap, and with grid == exact residency
// there is NO backfill -- a SIMD hosting slow waves convoys. Fix: grid 512
// blocks (still 2/CU, full residency); each wave processes its own chunk
// then pulls fresh 64-item chunks via atomicAdd. Per-item math bit-identical.
//
// u/v post-mortem (R2-R5, RESOLVED): with inconsistent marginals
// (sum rm != sum cm), u,v drift as alpha^t / alpha^-t; v underflows ->
// EPS floors the denominator -> finite-but-wrong (0.369); without EPS ->
// rcp(0)=inf -> NaN. Not toolchain pathology. Renormalized u/v (u[0]==1)
// is the bounded fix and remains the backup lever (~24% loop-op cut).
__global__ __launch_bounds__(256, 2) void sinkhorn_km_kernel(
    const float* __restrict__ margins,
    const float* __restrict__ W1, const float* __restrict__ b1,
    const float* __restrict__ W2, const float* __restrict__ b2,
    const float* __restrict__ W3, const float* __restrict__ b3,
    const float* __restrict__ Wtau,
    float* __restrict__ out, unsigned int* __restrict__ ticket,
    int B, int firstChunks)
{
    // mum0/mu0f/V parked in LDS during the loop; stride 13 conflict-free.
    // Epilogue reuses `side` as per-wave staging (all hazards intra-wave ->
    // barrier-free, R6 win). Wave slice = side[832w..832w+831] = exactly the
    // wave's 64 sd slots (64*13 = 832), so chunk reuse is also intra-wave.
    __shared__ float side[256 * 13];
    const int tid  = threadIdx.x;
    const int lane = tid & 63;
    const int wid  = tid >> 6;
    float* sd    = side + tid * 13;
    float* slice = side + wid * 832;
    const int NC = B >> 6;            // 64-item chunks; requires B % 64 == 0

    int chunk = blockIdx.x * 4 + wid; // first assignment: global wave id
    while (chunk < NC) {
        const int b = (chunk << 6) + lane;

        // ---- load 12 margins (coalesced float4)
        const float4* mp = (const float4*)(margins + (size_t)b * 12);
        float4 m0 = mp[0], m1 = mp[1], m2 = mp[2];
        float mar[12] = {m0.x, m0.y, m0.z, m0.w,
                         m1.x, m1.y, m1.z, m1.w,
                         m2.x, m2.y, m2.z, m2.w};

        // ---- MLP 12->32->16->18, packed 2-wide on the output dim
        const f32x2* W1v = (const f32x2*)W1;   // [12][16]
        const f32x2* b1v = (const f32x2*)b1;
        const f32x2* W2v = (const f32x2*)W2;   // [32][8]
        const f32x2* b2v = (const f32x2*)b2;
        const f32x2* W3v = (const f32x2*)W3;   // [16][9]
        const f32x2* b3v = (const f32x2*)b3;
        const f32x2* Wtv = (const f32x2*)Wtau; // [8][18]

        f32x2 h1v[16];
#pragma unroll
        for (int o = 0; o < 16; ++o) {
            f32x2 acc = b1v[o];
#pragma unroll
            for (int i = 0; i < 12; ++i) acc += splat2(mar[i]) * W1v[i * 16 + o];
            acc.x = acc.x > 0.0f ? acc.x : 0.0f;
            acc.y = acc.y > 0.0f ? acc.y : 0.0f;
            h1v[o] = acc;
        }
        f32x2 h2v[8];
#pragma unroll
        for (int o = 0; o < 8; ++o) {
            f32x2 acc = b2v[o];
#pragma unroll
            for (int i = 0; i < 32; ++i) {
                float hi = (i & 1) ? h1v[i >> 1].y : h1v[i >> 1].x;
                acc += splat2(hi) * W2v[i * 8 + o];
            }
            acc.x = acc.x > 0.0f ? acc.x : 0.0f;
            acc.y = acc.y > 0.0f ? acc.y : 0.0f;
            h2v[o] = acc;
        }
        float pars[18];
#pragma unroll
        for (int o = 0; o < 9; ++o) {
            f32x2 acc = b3v[o];
#pragma unroll
            for (int i = 0; i < 16; ++i) {
                float hi = (i & 1) ? h2v[i >> 1].y : h2v[i >> 1].x;
                acc += splat2(hi) * W3v[i * 9 + o];
            }
            pars[2 * o]     = acc.x;
            pars[2 * o + 1] = acc.y;
        }

        // ---- marginals; mum/muf/V go straight to LDS
        float shm[6] = {squash(pars[9]),  squash(pars[10]), 1.0f,
                        squash(pars[11]), squash(pars[12]), 1.0f};
        float shf[6] = {squash(pars[13]), squash(pars[14]), 1.0f,
                        squash(pars[15]), squash(pars[16]), 1.0f};
        float rm[6], cm[6];
#pragma unroll
        for (int j = 0; j < 6; ++j) {
            float Mj = mar[j], Fj = mar[6 + j];
            rm[j] = Mj * shm[j];         // mucm0 (row targets)
            cm[j] = Fj * shf[j];         // muc0f (col targets)
            sd[j]     = Mj - rm[j];      // mum0
            sd[6 + j] = Fj - cm[j];      // mu0f
        }
        sd[12] = __expf(pars[17]);       // V

        // ---- A = exp(einsum), packed: A2[i*3+p] = cols (2p,2p+1) of row i
        f32x2 A2[18];
#pragma unroll
        for (int p = 0; p < 18; ++p) {
            f32x2 acc = splat2(0.0f);
#pragma unroll
            for (int k = 0; k < 8; ++k) acc += splat2(pars[k]) * Wtv[k * 18 + p];
            f32x2 e; e.x = __expf(acc.x); e.y = __expf(acc.y);
            A2[p] = e;
        }

        // ---- Sinkhorn (matrix form, proven R0/R1/R6/R8), packed pairs.
        for (int t = 0; t < MAX_ITERS; ++t) {
            float f[6];
#pragma unroll
            for (int i = 0; i < 6; ++i) {
                f32x2 s2 = A2[i * 3 + 0] + A2[i * 3 + 1] + A2[i * 3 + 2];
                float s = s2.x + s2.y;
                float fi = rm[i] * fast_rcp(s + EPS);
                f[i] = fi;
                f32x2 fb = splat2(fi);
                A2[i * 3 + 0] *= fb;
                A2[i * 3 + 1] *= fb;
                A2[i * 3 + 2] *= fb;
            }
#pragma unroll
            for (int p = 0; p < 3; ++p) {
                f32x2 c2 = A2[0 * 3 + p] + A2[1 * 3 + p] + A2[2 * 3 + p]
                         + A2[3 * 3 + p] + A2[4 * 3 + p] + A2[5 * 3 + p];
                f32x2 g;
                g.x = cm[2 * p]     * fast_rcp(c2.x + EPS);
                g.y = cm[2 * p + 1] * fast_rcp(c2.y + EPS);
#pragma unroll
                for (int i = 0; i < 6; ++i) A2[i * 3 + p] *= g;
            }
            float fmax = fmaxf(fmaxf(fmaxf(f[0], f[1]), fmaxf(f[2], f[3])),
                               fmaxf(f[4], f[5]));
            float fmin = fminf(fminf(fminf(f[0], f[1]), fminf(f[2], f[3])),
                               fminf(f[4], f[5]));
            if (__all(fmax - fmin <= TOL * fmax)) break;
        }

        // ---- epilogue: coalesced stores via wave-local LDS staging,
        // barrier-free (R6). All hazards intra-wave; DS retires in program
        // order per wave; global stores fire-and-forget.
        float mum[6], muf[6];
#pragma unroll
        for (int j = 0; j < 6; ++j) { mum[j] = sd[j]; muf[j] = sd[6 + j]; }
        const float V = sd[12];

        float* gout = out + (size_t)chunk * 64 * 49;
#pragma unroll
        for (int r = 0; r < 4; ++r) {
            if ((lane >> 4) == r) {
                float* s = slice + (lane & 15) * 49;
#pragma unroll
                for (int i = 0; i < 6; ++i) {
#pragma unroll
                    for (int p = 0; p < 3; ++p) {
                        s[i * 7 + 2 * p]     = A2[i * 3 + p].x;
                        s[i * 7 + 2 * p + 1] = A2[i * 3 + p].y;
                    }
                    s[i * 7 + 6] = mum[i];
                }
#pragma unroll
                for (int j = 0; j < 6; ++j) s[42 + j] = muf[j];
                s[48] = 0.0f;
            }
            // drain 784 dwords = 3 x (64 lanes x float4) + 16-dword tail
            const float4* sv = (const float4*)slice;
            float4* gv = (float4*)(gout + r * 784);
#pragma unroll
            for (int j = 0; j < 3; ++j) gv[lane + j * 64] = sv[lane + j * 64];
            if (lane < 16) (gout + r * 784)[768 + lane] = slice[768 + lane];
        }
        // V stream: lane-consecutive dwords, coalesced
        out[(size_t)B * 49 + b] = V;

        // ---- next ticket (persistent-wave refill)
        if (firstChunks >= NC) break;   // fallback mode: no refills, no d_ws use
        unsigned int tk;
        if (lane == 0) tk = atomicAdd(ticket, 1u);
        tk = (unsigned int)__builtin_amdgcn_readfirstlane((int)tk);
        chunk = (int)(tk + (unsigned int)firstChunks);
    }
}

extern "C" void kernel_launch(void* const* d_in, const int* in_sizes, int n_in,
                              void* d_out, int out_size, void* d_ws, size_t ws_size,
                              hipStream_t stream) {
    const float* margins = (const float*)d_in[0];
    const float* W1   = (const float*)d_in[1];
    const float* b1   = (const float*)d_in[2];
    const float* W2   = (const float*)d_in[3];
    const float* b2   = (const float*)d_in[4];
    const float* W3   = (const float*)d_in[5];
    const float* b3   = (const float*)d_in[6];
    const float* Wtau = (const float*)d_in[7];
    const int B = in_sizes[0] / 12;
    const int NC = B / 64;              // B % 64 == 0 for this problem (524288)

    int nblocks = 512;                  // 2 blocks/CU on 256 CUs: full residency
    bool persistent = (d_ws != nullptr && ws_size >= sizeof(unsigned int));
    if (!persistent || nblocks * 4 > NC) {
        // fallback: one chunk per wave, no tickets
        nblocks = (NC + 3) / 4;
    }
    const int firstChunks = persistent ? nblocks * 4 : NC;

    if (persistent && firstChunks < NC) {
        hipMemsetAsync(d_ws, 0, sizeof(unsigned int), stream);  // graph-safe
    }

    dim3 block(256);
    dim3 grid(nblocks);
    hipLaunchKernelGGL(sinkhorn_km_kernel, grid, block, 0, stream,
                       margins, W1, b1, W2, b2, W3, b3, Wtau,
                       (float*)d_out, (unsigned int*)d_ws, B, firstChunks);
}

// Round 10
// 175.738 us; speedup vs baseline: 2.4453x; 2.4453x over previous
//
#include <hip/hip_runtime.h>
#include <math.h>

#define MAX_ITERS 100
#define EPS 1e-12f
// TOL 2e-4 (R7, neutral but safe): certifies ~7e-4 relative distance to the
// fixed point, ~5x under the 3.9e-3 bf16 floor, ~30x under the threshold.
#define TOL 2e-4f

// f32x2 packing (R8): NEUTRAL in the issue dimension (gfx950 has no
// double-rate packed f32), kept as the proven-green code shape.
typedef float f32x2 __attribute__((ext_vector_type(2)));

__device__ __forceinline__ f32x2 splat2(float x) { f32x2 r; r.x = x; r.y = x; return r; }

// v_rcp_f32: <=1 ulp. Proven neutral on absmax (bf16 floor 0.00390625).
__device__ __forceinline__ float fast_rcp(float x) {
    return __builtin_amdgcn_rcpf(x);
}

// _squash = 0.02 + 0.96*sigmoid(x); native exp + rcp.
__device__ __forceinline__ float squash(float x) {
    return 0.02f + 0.96f * fast_rcp(1.0f + __expf(-x));
}

// R10: SMALL-BLOCK BACKFILL. R9's residency blunder (512 blocks = 2
// waves/SIMD) exposed the true regime: latency-bound (VALU dep chains +
// ~740 uniform weight loads/item), hidden only by TLP -- 31% VALUBusy and
// ~19 cyc/inst when 2-deep. So the R6-R8 kernel's cost is dominated by the
// occupancy DRAIN as waves early-exit. Fix: 4096 blocks x 128 threads
// (2 waves/block) -- 2x the 16-blocks/CU residency capacity, so the HW
// scheduler backfills retired blocks and keeps SIMDs ~8 waves deep until
// global work exhausts. Per-item math bit-identical to R8.
//
// u/v post-mortem (R2-R5, RESOLVED): inconsistent marginals (sum rm !=
// sum cm) make u,v drift as alpha^t/alpha^-t; v underflows -> EPS floors
// the denominator -> finite-but-wrong; without EPS -> NaN. Not toolchain
// pathology. Renormalized u/v remains a backup op-count lever.
__global__ __launch_bounds__(128, 8) void sinkhorn_km_kernel(
    const float* __restrict__ margins,
    const float* __restrict__ W1, const float* __restrict__ b1,
    const float* __restrict__ W2, const float* __restrict__ b2,
    const float* __restrict__ W3, const float* __restrict__ b3,
    const float* __restrict__ Wtau,
    float* __restrict__ out, int B)
{
    // mum0/mu0f/V parked in LDS during the loop; stride 13 conflict-free.
    // Epilogue reuses `side` as per-wave staging (R6 win, barrier-free).
    // 128*13 = 1664 = 2 x 832: wave w's slice side[832w..832w+831] is
    // exactly its 64 threads' sd slots -- all hazards intra-wave, verbatim
    // the R6-proven argument.
    __shared__ float side[128 * 13];
    const int tid  = threadIdx.x;
    const int lane = tid & 63;
    const int wid  = tid >> 6;
    const int b = blockIdx.x * 128 + tid;
    if (b >= B) return;   // never fires (B % 128 == 0)
    float* sd    = side + tid * 13;
    float* slice = side + wid * 832;

    // ---- load 12 margins (coalesced float4; 48B/row, 16B aligned)
    const float4* mp = (const float4*)(margins + (size_t)b * 12);
    float4 m0 = mp[0], m1 = mp[1], m2 = mp[2];
    float mar[12] = {m0.x, m0.y, m0.z, m0.w,
                     m1.x, m1.y, m1.z, m1.w,
                     m2.x, m2.y, m2.z, m2.w};

    // ---- MLP 12->32->16->18, packed 2-wide on the output dim
    const f32x2* W1v = (const f32x2*)W1;   // [12][16]
    const f32x2* b1v = (const f32x2*)b1;
    const f32x2* W2v = (const f32x2*)W2;   // [32][8]
    const f32x2* b2v = (const f32x2*)b2;
    const f32x2* W3v = (const f32x2*)W3;   // [16][9]
    const f32x2* b3v = (const f32x2*)b3;
    const f32x2* Wtv = (const f32x2*)Wtau; // [8][18]

    f32x2 h1v[16];
#pragma unroll
    for (int o = 0; o < 16; ++o) {
        f32x2 acc = b1v[o];
#pragma unroll
        for (int i = 0; i < 12; ++i) acc += splat2(mar[i]) * W1v[i * 16 + o];
        acc.x = acc.x > 0.0f ? acc.x : 0.0f;
        acc.y = acc.y > 0.0f ? acc.y : 0.0f;
        h1v[o] = acc;
    }
    f32x2 h2v[8];
#pragma unroll
    for (int o = 0; o < 8; ++o) {
        f32x2 acc = b2v[o];
#pragma unroll
        for (int i = 0; i < 32; ++i) {
            float hi = (i & 1) ? h1v[i >> 1].y : h1v[i >> 1].x;
            acc += splat2(hi) * W2v[i * 8 + o];
        }
        acc.x = acc.x > 0.0f ? acc.x : 0.0f;
        acc.y = acc.y > 0.0f ? acc.y : 0.0f;
        h2v[o] = acc;
    }
    float pars[18];
#pragma unroll
    for (int o = 0; o < 9; ++o) {
        f32x2 acc = b3v[o];
#pragma unroll
        for (int i = 0; i < 16; ++i) {
            float hi = (i & 1) ? h2v[i >> 1].y : h2v[i >> 1].x;
            acc += splat2(hi) * W3v[i * 9 + o];
        }
        pars[2 * o]     = acc.x;
        pars[2 * o + 1] = acc.y;
    }

    // ---- marginals; mum/muf/V go straight to LDS
    float shm[6] = {squash(pars[9]),  squash(pars[10]), 1.0f,
                    squash(pars[11]), squash(pars[12]), 1.0f};
    float shf[6] = {squash(pars[13]), squash(pars[14]), 1.0f,
                    squash(pars[15]), squash(pars[16]), 1.0f};
    float rm[6], cm[6];
#pragma unroll
    for (int j = 0; j < 6; ++j) {
        float Mj = mar[j], Fj = mar[6 + j];
        rm[j] = Mj * shm[j];         // mucm0 (row targets)
        cm[j] = Fj * shf[j];         // muc0f (col targets)
        sd[j]     = Mj - rm[j];      // mum0
        sd[6 + j] = Fj - cm[j];      // mu0f
    }
    sd[12] = __expf(pars[17]);       // V

    // ---- A = exp(einsum), packed: A2[i*3+p] = cols (2p,2p+1) of row i
    f32x2 A2[18];
#pragma unroll
    for (int p = 0; p < 18; ++p) {
        f32x2 acc = splat2(0.0f);
#pragma unroll
        for (int k = 0; k < 8; ++k) acc += splat2(pars[k]) * Wtv[k * 18 + p];
        f32x2 e; e.x = __expf(acc.x); e.y = __expf(acc.y);
        A2[p] = e;
    }

    // ---- Sinkhorn (matrix form, proven R0/R1/R6/R8), packed pairs.
    for (int t = 0; t < MAX_ITERS; ++t) {
        float f[6];
#pragma unroll
        for (int i = 0; i < 6; ++i) {
            f32x2 s2 = A2[i * 3 + 0] + A2[i * 3 + 1] + A2[i * 3 + 2];
            float s = s2.x + s2.y;
            float fi = rm[i] * fast_rcp(s + EPS);
            f[i] = fi;
            f32x2 fb = splat2(fi);
            A2[i * 3 + 0] *= fb;
            A2[i * 3 + 1] *= fb;
            A2[i * 3 + 2] *= fb;
        }
#pragma unroll
        for (int p = 0; p < 3; ++p) {
            f32x2 c2 = A2[0 * 3 + p] + A2[1 * 3 + p] + A2[2 * 3 + p]
                     + A2[3 * 3 + p] + A2[4 * 3 + p] + A2[5 * 3 + p];
            f32x2 g;
            g.x = cm[2 * p]     * fast_rcp(c2.x + EPS);
            g.y = cm[2 * p + 1] * fast_rcp(c2.y + EPS);
#pragma unroll
            for (int i = 0; i < 6; ++i) A2[i * 3 + p] *= g;
        }
        float fmax = fmaxf(fmaxf(fmaxf(f[0], f[1]), fmaxf(f[2], f[3])),
                           fmaxf(f[4], f[5]));
        float fmin = fminf(fminf(fminf(f[0], f[1]), fminf(f[2], f[3])),
                           fminf(f[4], f[5]));
        if (__all(fmax - fmin <= TOL * fmax)) break;
    }

    // ---- epilogue: coalesced stores via wave-local LDS staging,
    // barrier-free (R6, verified green). All hazards intra-wave; DS retires
    // in program order per wave; global stores fire-and-forget; waves retire
    // independently -> small blocks retire fast -> HW backfills.
    float mum[6], muf[6];
#pragma unroll
    for (int j = 0; j < 6; ++j) { mum[j] = sd[j]; muf[j] = sd[6 + j]; }
    const float V = sd[12];

    float* gout = out + ((size_t)blockIdx.x * 128 + (size_t)wid * 64) * 49;

#pragma unroll
    for (int r = 0; r < 4; ++r) {
        if ((lane >> 4) == r) {
            float* s = slice + (lane & 15) * 49;
#pragma unroll
            for (int i = 0; i < 6; ++i) {
#pragma unroll
                for (int p = 0; p < 3; ++p) {
                    s[i * 7 + 2 * p]     = A2[i * 3 + p].x;
                    s[i * 7 + 2 * p + 1] = A2[i * 3 + p].y;
                }
                s[i * 7 + 6] = mum[i];
            }
#pragma unroll
            for (int j = 0; j < 6; ++j) s[42 + j] = muf[j];
            s[48] = 0.0f;
        }
        // drain 784 dwords = 3 x (64 lanes x float4) + 16-dword tail
        const float4* sv = (const float4*)slice;
        float4* gv = (float4*)(gout + r * 784);
#pragma unroll
        for (int j = 0; j < 3; ++j) gv[lane + j * 64] = sv[lane + j * 64];
        if (lane < 16) (gout + r * 784)[768 + lane] = slice[768 + lane];
    }
    // V stream: lane-consecutive dwords, coalesced
    out[(size_t)B * 49 + b] = V;
}

extern "C" void kernel_launch(void* const* d_in, const int* in_sizes, int n_in,
                              void* d_out, int out_size, void* d_ws, size_t ws_size,
                              hipStream_t stream) {
    const float* margins = (const float*)d_in[0];
    const float* W1   = (const float*)d_in[1];
    const float* b1   = (const float*)d_in[2];
    const float* W2   = (const float*)d_in[3];
    const float* b2   = (const float*)d_in[4];
    const float* W3   = (const float*)d_in[5];
    const float* b3   = (const float*)d_in[6];
    const float* Wtau = (const float*)d_in[7];
    const int B = in_sizes[0] / 12;

    // 128-thread blocks (2 waves): 16 blocks/CU resident = 8 waves/SIMD,
    // grid = 2x residency capacity -> HW backfill keeps SIMDs deep through
    // the convergence tail (R10 lever).
    dim3 block(128);
    dim3 grid((B + 127) / 128);
    hipLaunchKernelGGL(sinkhorn_km_kernel, grid, block, 0, stream,
                       margins, W1, b1, W2, b2, W3, b3, Wtau,
                       (float*)d_out, B);
}

// Round 11
// 161.182 us; speedup vs baseline: 2.6661x; 1.0903x over previous
//
#include <hip/hip_runtime.h>
#include <math.h>

#define MAX_ITERS 100
// TOL 2e-4 (R7, neutral but safe): certifies ~7e-4 relative distance to the
// fixed point, ~5x under the 3.9e-3 bf16 floor. Slow items (r>~0.92) are
// CAP-bound at 100 iters under any tolerance (R7/R10 analysis).
#define TOL 2e-4f

// f32x2 packing (R8): neutral in the issue dimension (gfx950 has no
// double-rate packed f32), kept as the proven-green code shape.
typedef float f32x2 __attribute__((ext_vector_type(2)));

__device__ __forceinline__ f32x2 splat2(float x) { f32x2 r; r.x = x; r.y = x; return r; }

// v_rcp_f32: <=1 ulp. Proven neutral on absmax (bf16 floor 0.00390625).
__device__ __forceinline__ float fast_rcp(float x) {
    return __builtin_amdgcn_rcpf(x);
}

// _squash = 0.02 + 0.96*sigmoid(x); native exp + rcp.
__device__ __forceinline__ float squash(float x) {
    return 0.02f + 0.96f * fast_rcp(1.0f + __expf(-x));
}

// R11: revert to the PROVEN R8 config (256 thr, (256,2), VGPR 48, kernel
// ~58us) and cut per-iteration issue slots on the matrix form:
//  - in-loop EPS dropped: matrix-form denominators are strictly positive
//    and O(>=1e-5) -- every A entry is a product of positive factors and
//    the alternating row/col re-normalization prevents any monotone decay
//    (unlike u/v, whose unbounded alpha^t scale drift caused R4/R5's
//    NaN / EPS-floored-wrong results). s > 0 strictly => no inf/NaN.
//  - convergence test every 2nd iter (wave-uniform t) -- ~7 slots/iter avg.
//  - max3/min3-shaped reduction trees for the spread test.
// R10 lesson (launch_bounds(128,8) -> VGPR 32 -> scratch spills -> FETCH
// 12.5->46.6MB, WRITE 102->170MB, 71us): never cap VGPR below ~48 here.
// Backfill is structurally impossible: B/64 = 8192 waves = exact chip wave
// capacity; the convergence tail is cap-bound, not scheduling-bound.
__global__ __launch_bounds__(256, 2) void sinkhorn_km_kernel(
    const float* __restrict__ margins,
    const float* __restrict__ W1, const float* __restrict__ b1,
    const float* __restrict__ W2, const float* __restrict__ b2,
    const float* __restrict__ W3, const float* __restrict__ b3,
    const float* __restrict__ Wtau,
    float* __restrict__ out, int B)
{
    // mum0/mu0f/V parked in LDS during the loop; stride 13 conflict-free.
    // Epilogue reuses `side` as per-wave staging (R6 win, barrier-free):
    // wave w's slice side[832w..832w+831] == its 64 threads' sd slots, so
    // all epilogue LDS hazards are intra-wave (DS retires in program order
    // per wave; compiler orders may-aliasing ds ops). No __syncthreads.
    __shared__ float side[256 * 13];
    const int tid  = threadIdx.x;
    const int lane = tid & 63;
    const int wid  = tid >> 6;
    const int b = blockIdx.x * 256 + tid;
    if (b >= B) return;   // never fires (B % 256 == 0)
    float* sd    = side + tid * 13;
    float* slice = side + wid * 832;

    // ---- load 12 margins (coalesced float4; 48B/row, 16B aligned)
    const float4* mp = (const float4*)(margins + (size_t)b * 12);
    float4 m0 = mp[0], m1 = mp[1], m2 = mp[2];
    float mar[12] = {m0.x, m0.y, m0.z, m0.w,
                     m1.x, m1.y, m1.z, m1.w,
                     m2.x, m2.y, m2.z, m2.w};

    // ---- MLP 12->32->16->18, packed 2-wide on the output dim
    const f32x2* W1v = (const f32x2*)W1;   // [12][16]
    const f32x2* b1v = (const f32x2*)b1;
    const f32x2* W2v = (const f32x2*)W2;   // [32][8]
    const f32x2* b2v = (const f32x2*)b2;
    const f32x2* W3v = (const f32x2*)W3;   // [16][9]
    const f32x2* b3v = (const f32x2*)b3;
    const f32x2* Wtv = (const f32x2*)Wtau; // [8][18]

    f32x2 h1v[16];
#pragma unroll
    for (int o = 0; o < 16; ++o) {
        f32x2 acc = b1v[o];
#pragma unroll
        for (int i = 0; i < 12; ++i) acc += splat2(mar[i]) * W1v[i * 16 + o];
        acc.x = acc.x > 0.0f ? acc.x : 0.0f;
        acc.y = acc.y > 0.0f ? acc.y : 0.0f;
        h1v[o] = acc;
    }
    f32x2 h2v[8];
#pragma unroll
    for (int o = 0; o < 8; ++o) {
        f32x2 acc = b2v[o];
#pragma unroll
        for (int i = 0; i < 32; ++i) {
            float hi = (i & 1) ? h1v[i >> 1].y : h1v[i >> 1].x;
            acc += splat2(hi) * W2v[i * 8 + o];
        }
        acc.x = acc.x > 0.0f ? acc.x : 0.0f;
        acc.y = acc.y > 0.0f ? acc.y : 0.0f;
        h2v[o] = acc;
    }
    float pars[18];
#pragma unroll
    for (int o = 0; o < 9; ++o) {
        f32x2 acc = b3v[o];
#pragma unroll
        for (int i = 0; i < 16; ++i) {
            float hi = (i & 1) ? h2v[i >> 1].y : h2v[i >> 1].x;
            acc += splat2(hi) * W3v[i * 9 + o];
        }
        pars[2 * o]     = acc.x;
        pars[2 * o + 1] = acc.y;
    }

    // ---- marginals; mum/muf/V go straight to LDS
    float shm[6] = {squash(pars[9]),  squash(pars[10]), 1.0f,
                    squash(pars[11]), squash(pars[12]), 1.0f};
    float shf[6] = {squash(pars[13]), squash(pars[14]), 1.0f,
                    squash(pars[15]), squash(pars[16]), 1.0f};
    float rm[6], cm[6];
#pragma unroll
    for (int j = 0; j < 6; ++j) {
        float Mj = mar[j], Fj = mar[6 + j];
        rm[j] = Mj * shm[j];         // mucm0 (row targets)
        cm[j] = Fj * shf[j];         // muc0f (col targets)
        sd[j]     = Mj - rm[j];      // mum0
        sd[6 + j] = Fj - cm[j];      // mu0f
    }
    sd[12] = __expf(pars[17]);       // V

    // ---- A = exp(einsum), packed: A2[i*3+p] = cols (2p,2p+1) of row i
    f32x2 A2[18];
#pragma unroll
    for (int p = 0; p < 18; ++p) {
        f32x2 acc = splat2(0.0f);
#pragma unroll
        for (int k = 0; k < 8; ++k) acc += splat2(pars[k]) * Wtv[k * 18 + p];
        f32x2 e; e.x = __expf(acc.x); e.y = __expf(acc.y);
        A2[p] = e;
    }

    // ---- Sinkhorn (matrix form, proven R0/R1/R6/R8), packed pairs.
    // In-loop EPS dropped (denominators strictly positive, see header note);
    // convergence test every 2nd iteration; max3/min3 reduction trees.
    for (int t = 0; t < MAX_ITERS; ++t) {
        float f[6];
#pragma unroll
        for (int i = 0; i < 6; ++i) {
            f32x2 s2 = A2[i * 3 + 0] + A2[i * 3 + 1] + A2[i * 3 + 2];
            float s = s2.x + s2.y;
            float fi = rm[i] * fast_rcp(s);
            f[i] = fi;
            f32x2 fb = splat2(fi);
            A2[i * 3 + 0] *= fb;
            A2[i * 3 + 1] *= fb;
            A2[i * 3 + 2] *= fb;
        }
#pragma unroll
        for (int p = 0; p < 3; ++p) {
            f32x2 c2 = A2[0 * 3 + p] + A2[1 * 3 + p] + A2[2 * 3 + p]
                     + A2[3 * 3 + p] + A2[4 * 3 + p] + A2[5 * 3 + p];
            f32x2 g;
            g.x = cm[2 * p]     * fast_rcp(c2.x);
            g.y = cm[2 * p + 1] * fast_rcp(c2.y);
#pragma unroll
            for (int i = 0; i < 6; ++i) A2[i * 3 + p] *= g;
        }
        if (t & 1) {
            // nested triples -> v_max3/v_min3 fusion (3+3 ops vs 5+5)
            float fmax = fmaxf(fmaxf(fmaxf(fmaxf(f[0], f[1]), f[2]), fmaxf(f[3], f[4])), f[5]);
            float fmin = fminf(fminf(fminf(fminf(f[0], f[1]), f[2]), fminf(f[3], f[4])), f[5]);
            if (__all(fmax - fmin <= TOL * fmax)) break;
        }
    }

    // ---- epilogue: coalesced stores via wave-local LDS staging,
    // barrier-free (R6, verified green). Global stores fire-and-forget;
    // waves retire independently.
    float mum[6], muf[6];
#pragma unroll
    for (int j = 0; j < 6; ++j) { mum[j] = sd[j]; muf[j] = sd[6 + j]; }
    const float V = sd[12];

    float* gout = out + ((size_t)blockIdx.x * 256 + (size_t)wid * 64) * 49;

#pragma unroll
    for (int r = 0; r < 4; ++r) {
        if ((lane >> 4) == r) {
            float* s = slice + (lane & 15) * 49;
#pragma unroll
            for (int i = 0; i < 6; ++i) {
#pragma unroll
                for (int p = 0; p < 3; ++p) {
                    s[i * 7 + 2 * p]     = A2[i * 3 + p].x;
                    s[i * 7 + 2 * p + 1] = A2[i * 3 + p].y;
                }
                s[i * 7 + 6] = mum[i];
            }
#pragma unroll
            for (int j = 0; j < 6; ++j) s[42 + j] = muf[j];
            s[48] = 0.0f;
        }
        // drain 784 dwords = 3 x (64 lanes x float4) + 16-dword tail
        const float4* sv = (const float4*)slice;
        float4* gv = (float4*)(gout + r * 784);
#pragma unroll
        for (int j = 0; j < 3; ++j) gv[lane + j * 64] = sv[lane + j * 64];
        if (lane < 16) (gout + r * 784)[768 + lane] = slice[768 + lane];
    }
    // V stream: lane-consecutive dwords, coalesced
    out[(size_t)B * 49 + b] = V;
}

extern "C" void kernel_launch(void* const* d_in, const int* in_sizes, int n_in,
                              void* d_out, int out_size, void* d_ws, size_t ws_size,
                              hipStream_t stream) {
    const float* margins = (const float*)d_in[0];
    const float* W1   = (const float*)d_in[1];
    const float* b1   = (const float*)d_in[2];
    const float* W2   = (const float*)d_in[3];
    const float* b2   = (const float*)d_in[4];
    const float* W3   = (const float*)d_in[5];
    const float* b3   = (const float*)d_in[6];
    const float* Wtau = (const float*)d_in[7];
    const int B = in_sizes[0] / 12;

    dim3 block(256);
    dim3 grid((B + 255) / 256);
    hipLaunchKernelGGL(sinkhorn_km_kernel, grid, block, 0, stream,
                       margins, W1, b1, W2, b2, W3, b3, Wtau,
                       (float*)d_out, B);
}